// Round 1
// baseline (259.122 us; speedup 1.0000x reference)
//
#include <hip/hip_runtime.h>

typedef unsigned short u16;
typedef __attribute__((ext_vector_type(8))) short short8;
typedef __attribute__((ext_vector_type(4))) float f32x4;

typedef const __attribute__((address_space(1))) void* gptr_t;
typedef __attribute__((address_space(3))) void* sptr_t;

#define B_SZ 2
#define N_SEQ 2048
#define DIM 1024
#define INNER 1024
#define HEADS 16
#define DHEAD 64
#define NTOK 4096            // B*N
#define QKV_LD 3072
#define ATT_SCALE 0.125f     // 64^-0.5

__device__ __forceinline__ u16 f2b(float f) {
  union { float f; unsigned u; } v; v.f = f;
  unsigned r = v.u + 0x7fffu + ((v.u >> 16) & 1u);
  return (u16)(r >> 16);
}

// ---------------- cast x: fp32 -> bf16, 8 elems/thread ----------------
__global__ __launch_bounds__(256) void cast_x_kernel(const float* __restrict__ src,
                                                     u16* __restrict__ dst) {
  const size_t i = (size_t)blockIdx.x * 256 + threadIdx.x;
  const f32x4* s = (const f32x4*)(src + i * 8);
  f32x4 a = s[0], b = s[1];
  short8 o;
#pragma unroll
  for (int j = 0; j < 4; ++j) { o[j] = (short)f2b(a[j]); o[4 + j] = (short)f2b(b[j]); }
  *(short8*)(dst + i * 8) = o;
}

// ------------- transpose+cast W[1024][1024] f32 -> Wt[1024][1024] bf16 -------------
__global__ __launch_bounds__(256) void transpose_cast_kernel(const float* __restrict__ src,
                                                             u16* __restrict__ dst) {
  __shared__ u16 tile[64][65];
  const int n0 = blockIdx.x * 64, k0 = blockIdx.y * 64;
  for (int i = threadIdx.x; i < 4096; i += 256) {
    const int r = i >> 6, c = i & 63;
    tile[r][c] = f2b(src[(size_t)(k0 + r) * 1024 + n0 + c]);
  }
  __syncthreads();
  for (int i = threadIdx.x; i < 4096; i += 256) {
    const int r = i >> 6, c = i & 63;
    dst[(size_t)(n0 + r) * 1024 + k0 + c] = tile[c][r];
  }
}

// ---------------- TN GEMM: C[M][N] = A[M][K] * Bt[N][K]^T  (m97 structure) ----------------
template <typename OutT>
__global__ __launch_bounds__(256) void gemm_tn(const u16* __restrict__ A,
                                               const u16* __restrict__ Bt,
                                               OutT* __restrict__ C,
                                               int M, int N, int K) {
  __shared__ u16 Al[128 * 64];
  __shared__ u16 Bl[128 * 64];
  const int tid = threadIdx.x;
  const int w = tid >> 6, lane = tid & 63;
  const int l15 = lane & 15, lg = lane >> 4;
  const int wr = w >> 1, wc = w & 1;
  const int m0 = blockIdx.y * 128, n0 = blockIdx.x * 128;

  f32x4 acc[4][4] = {};

  for (int k0 = 0; k0 < K; k0 += 64) {
#pragma unroll
    for (int i = 0; i < 4; ++i) {
      const int chunk = (w << 2) + i;               // 0..15, wave-uniform
      const int e = (chunk << 9) + lane * 8;        // element offset in tile
      const int row = e >> 6, col = e & 63;
      const u16* ga = A + (size_t)(m0 + row) * K + k0 + col;
      __builtin_amdgcn_global_load_lds((gptr_t)ga, (sptr_t)(Al + (chunk << 9)), 16, 0, 0);
      const u16* gb = Bt + (size_t)(n0 + row) * K + k0 + col;
      __builtin_amdgcn_global_load_lds((gptr_t)gb, (sptr_t)(Bl + (chunk << 9)), 16, 0, 0);
    }
    __syncthreads();   // drains vmcnt(0) before any ds_read
#pragma unroll
    for (int kk = 0; kk < 2; ++kk) {
      short8 af[4], bf[4];
#pragma unroll
      for (int m = 0; m < 4; ++m)
        af[m] = *(const short8*)(Al + ((wr * 64 + m * 16 + l15) << 6) + kk * 32 + lg * 8);
#pragma unroll
      for (int n = 0; n < 4; ++n)
        bf[n] = *(const short8*)(Bl + ((wc * 64 + n * 16 + l15) << 6) + kk * 32 + lg * 8);
#pragma unroll
      for (int m = 0; m < 4; ++m)
#pragma unroll
        for (int n = 0; n < 4; ++n)
          acc[m][n] = __builtin_amdgcn_mfma_f32_16x16x32_bf16(af[m], bf[n], acc[m][n], 0, 0, 0);
    }
    __syncthreads();   // protect LDS before next stage
  }

#pragma unroll
  for (int m = 0; m < 4; ++m)
#pragma unroll
    for (int n = 0; n < 4; ++n)
#pragma unroll
      for (int r = 0; r < 4; ++r) {
        const int row = m0 + wr * 64 + m * 16 + lg * 4 + r;   // C/D: col=lane&15, row=(lane>>4)*4+reg
        const int col = n0 + wc * 64 + n * 16 + l15;
        const float v = acc[m][n][r];
        if constexpr (sizeof(OutT) == 2) C[(size_t)row * N + col] = (OutT)f2b(v);
        else                             C[(size_t)row * N + col] = (OutT)v;
      }
}

// ---------------- causal flash attention ----------------
// grid (32 q-tiles, 32 b*h), 256 thr. Block: 64 q-rows, wave w owns rows w*16..+16.
__global__ __launch_bounds__(256) void attn_kernel(const u16* __restrict__ qkv,
                                                   u16* __restrict__ attnb) {
  const int qt = blockIdx.x, bh = blockIdx.y;
  const int b = bh >> 4, h = bh & 15;
  const int tid = threadIdx.x;
  const int w = tid >> 6, lane = tid & 63;
  const int l15 = lane & 15, lg = lane >> 4;
  const int q0 = qt * 64;

  __shared__ u16 Kl[64][72];       // +8 pad: keeps 16B align (144B rows), 4-bank row shift
  __shared__ u16 Vt[64][72];       // V transposed: Vt[d][kv]
  __shared__ u16 Pl[4][16][72];    // per-wave P re-layout buffer

  const u16* base = qkv + (size_t)b * N_SEQ * QKV_LD;

  // Q fragments: row=lane&15, k(d)= (lane>>4)*8+j, contiguous 16B
  short8 aq[2];
  {
    const u16* qp = base + (size_t)(q0 + w * 16 + l15) * QKV_LD + h * 64 + lg * 8;
    aq[0] = *(const short8*)qp;
    aq[1] = *(const short8*)(qp + 32);
  }

  f32x4 o[4] = {};
  float m_run[4], l_run[4];
#pragma unroll
  for (int r = 0; r < 4; ++r) { m_run[r] = -__builtin_inff(); l_run[r] = 0.f; }

  for (int jt = 0; jt <= qt; ++jt) {
    const int kv0 = jt * 64;
    __syncthreads();               // previous tile's LDS reads done before overwrite
#pragma unroll
    for (int ch = tid; ch < 512; ch += 256) {
      const int r = ch >> 3, c = (ch & 7) * 8;
      const u16* kp = base + (size_t)(kv0 + r) * QKV_LD + 1024 + h * 64 + c;
      *(short8*)&Kl[r][c] = *(const short8*)kp;
      const u16* vp = base + (size_t)(kv0 + r) * QKV_LD + 2048 + h * 64 + c;
      short8 vv = *(const short8*)vp;
#pragma unroll
      for (int j = 0; j < 8; ++j) Vt[c + j][r] = ((u16*)&vv)[j];
    }
    __syncthreads();

    // S = Q K^T  (K rows are B-operand cols; k-dim = d, contiguous in LDS)
    f32x4 s[4];
#pragma unroll
    for (int nf = 0; nf < 4; ++nf) {
      f32x4 accs = {};
#pragma unroll
      for (int t = 0; t < 2; ++t) {
        short8 bk = *(const short8*)&Kl[nf * 16 + l15][t * 32 + lg * 8];
        accs = __builtin_amdgcn_mfma_f32_16x16x32_bf16(aq[t], bk, accs, 0, 0, 0);
      }
      s[nf] = accs;
    }

    const bool diag = (jt == qt);
#pragma unroll
    for (int nf = 0; nf < 4; ++nf)
#pragma unroll
      for (int r = 0; r < 4; ++r) {
        float sv = s[nf][r] * ATT_SCALE;
        if (diag) {
          const int col = kv0 + nf * 16 + l15;
          const int row = q0 + w * 16 + lg * 4 + r;
          if (col > row) sv = -__builtin_inff();
        }
        s[nf][r] = sv;
      }

    // wave-parallel row max over 64 kv cols (reduce across the 16-lane col group)
    float mt[4];
#pragma unroll
    for (int r = 0; r < 4; ++r)
      mt[r] = fmaxf(fmaxf(s[0][r], s[1][r]), fmaxf(s[2][r], s[3][r]));
#pragma unroll
    for (int x = 1; x < 16; x <<= 1)
#pragma unroll
      for (int r = 0; r < 4; ++r)
        mt[r] = fmaxf(mt[r], __shfl_xor(mt[r], x, 64));

    float sf[4], psum[4];
#pragma unroll
    for (int r = 0; r < 4; ++r) {
      const float mn = fmaxf(m_run[r], mt[r]);
      sf[r] = __expf(m_run[r] - mn);   // 0 on first tile (exp(-inf))
      m_run[r] = mn;
      psum[r] = 0.f;
    }
#pragma unroll
    for (int nf = 0; nf < 4; ++nf)
#pragma unroll
      for (int r = 0; r < 4; ++r) {
        const float p = __expf(s[nf][r] - m_run[r]);
        s[nf][r] = p;
        psum[r] += p;
      }
#pragma unroll
    for (int x = 1; x < 16; x <<= 1)
#pragma unroll
      for (int r = 0; r < 4; ++r)
        psum[r] += __shfl_xor(psum[r], x, 64);
#pragma unroll
    for (int r = 0; r < 4; ++r)
      l_run[r] = l_run[r] * sf[r] + psum[r];
#pragma unroll
    for (int df = 0; df < 4; ++df)
#pragma unroll
      for (int r = 0; r < 4; ++r)
        o[df][r] *= sf[r];

    // P (C-layout) -> per-wave LDS -> A-operand layout
#pragma unroll
    for (int nf = 0; nf < 4; ++nf)
#pragma unroll
      for (int r = 0; r < 4; ++r)
        Pl[w][lg * 4 + r][nf * 16 + l15] = f2b(s[nf][r]);
    asm volatile("s_waitcnt lgkmcnt(0)" ::: "memory");  // wave-local write->read fence

    short8 ap[2];
    ap[0] = *(const short8*)&Pl[w][l15][lg * 8];
    ap[1] = *(const short8*)&Pl[w][l15][32 + lg * 8];
#pragma unroll
    for (int df = 0; df < 4; ++df)
#pragma unroll
      for (int ks = 0; ks < 2; ++ks) {
        short8 bv = *(const short8*)&Vt[df * 16 + l15][ks * 32 + lg * 8];
        o[df] = __builtin_amdgcn_mfma_f32_16x16x32_bf16(ap[ks], bv, o[df], 0, 0, 0);
      }
  }

#pragma unroll
  for (int r = 0; r < 4; ++r) l_run[r] = 1.f / l_run[r];
#pragma unroll
  for (int df = 0; df < 4; ++df)
#pragma unroll
    for (int r = 0; r < 4; ++r) {
      const size_t row = (size_t)b * N_SEQ + q0 + w * 16 + lg * 4 + r;
      attnb[row * INNER + h * 64 + df * 16 + l15] = f2b(o[df][r] * l_run[r]);
    }
}

extern "C" void kernel_launch(void* const* d_in, const int* in_sizes, int n_in,
                              void* d_out, int out_size, void* d_ws, size_t ws_size,
                              hipStream_t stream) {
  const float* x  = (const float*)d_in[0];
  const float* Wq = (const float*)d_in[1];
  const float* Wk = (const float*)d_in[2];
  const float* Wv = (const float*)d_in[3];
  const float* Wo = (const float*)d_in[4];
  float* out = (float*)d_out;

  // workspace layout (bf16 elements): 48 MB total
  u16* xb    = (u16*)d_ws;                               // [4096][1024]
  u16* wqkvt = xb    + (size_t)NTOK * DIM;               // [3072][1024]  (Wq^T|Wk^T|Wv^T)
  u16* wot   = wqkvt + (size_t)3 * INNER * DIM;          // [1024][1024]  Wo^T
  u16* qkv   = wot   + (size_t)DIM * INNER;              // [4096][3072]
  u16* attnb = qkv   + (size_t)NTOK * QKV_LD;            // [4096][1024]

  cast_x_kernel<<<dim3(NTOK * DIM / (256 * 8)), 256, 0, stream>>>(x, xb);
  transpose_cast_kernel<<<dim3(16, 16), 256, 0, stream>>>(Wq, wqkvt);
  transpose_cast_kernel<<<dim3(16, 16), 256, 0, stream>>>(Wk, wqkvt + (size_t)1024 * 1024);
  transpose_cast_kernel<<<dim3(16, 16), 256, 0, stream>>>(Wv, wqkvt + (size_t)2048 * 1024);
  transpose_cast_kernel<<<dim3(16, 16), 256, 0, stream>>>(Wo, wot);

  gemm_tn<u16><<<dim3(3072 / 128, 4096 / 128), 256, 0, stream>>>(xb, wqkvt, qkv, NTOK, 3072, DIM);
  attn_kernel<<<dim3(32, 32), 256, 0, stream>>>(qkv, attnb);
  gemm_tn<float><<<dim3(1024 / 128, 4096 / 128), 256, 0, stream>>>(attnb, wot, out, NTOK, INNER, INNER);
}

// Round 3
// 153.153 us; speedup vs baseline: 1.6919x; 1.6919x over previous
//
#include <hip/hip_runtime.h>

typedef unsigned short u16;
typedef unsigned int u32;
typedef __attribute__((ext_vector_type(8))) short short8;
typedef __attribute__((ext_vector_type(4))) short s16x4;
typedef __attribute__((ext_vector_type(4))) float f32x4;
typedef __attribute__((ext_vector_type(2))) u32 u32x2;

typedef const __attribute__((address_space(1))) void* gptr_t;
typedef __attribute__((address_space(3))) void* sptr_t;

#define N_SEQ 2048
#define DIM 1024
#define INNER 1024
#define NTOK 4096
#define QKV_LD 3072

__device__ __forceinline__ u16 f2b(float f) {
  union { float f; unsigned u; } v; v.f = f;
  unsigned r = v.u + 0x7fffu + ((v.u >> 16) & 1u);
  return (u16)(r >> 16);
}

// ---------------- cast x: fp32 -> bf16, 8 elems/thread ----------------
__global__ __launch_bounds__(256) void cast_x_kernel(const float* __restrict__ src,
                                                     u16* __restrict__ dst) {
  const size_t i = (size_t)blockIdx.x * 256 + threadIdx.x;
  const f32x4* s = (const f32x4*)(src + i * 8);
  f32x4 a = s[0], b = s[1];
  short8 o;
#pragma unroll
  for (int j = 0; j < 4; ++j) { o[j] = (short)f2b(a[j]); o[4 + j] = (short)f2b(b[j]); }
  *(short8*)(dst + i * 8) = o;
}

// ------------- transpose+cast W[1024][1024] f32 -> Wt[1024][1024] bf16 -------------
__global__ __launch_bounds__(256) void transpose_cast_kernel(const float* __restrict__ src,
                                                             u16* __restrict__ dst) {
  __shared__ u16 tile[64][65];
  const int n0 = blockIdx.x * 64, k0 = blockIdx.y * 64;
  for (int i = threadIdx.x; i < 4096; i += 256) {
    const int r = i >> 6, c = i & 63;
    tile[r][c] = f2b(src[(size_t)(k0 + r) * 1024 + n0 + c]);
  }
  __syncthreads();
  for (int i = threadIdx.x; i < 4096; i += 256) {
    const int r = i >> 6, c = i & 63;
    dst[(size_t)(n0 + r) * 1024 + k0 + c] = tile[c][r];
  }
}

// ------------- transpose V portion of qkv -> vt[bh][64][2048] bf16 -------------
__global__ __launch_bounds__(256) void transpose_v_kernel(const u16* __restrict__ qkv,
                                                          u16* __restrict__ vt) {
  __shared__ u16 t[64][72];
  const int nt0 = blockIdx.x * 64;
  const int bh = blockIdx.y;
  const int b = bh >> 4, h = bh & 15;
  const u16* src = qkv + (size_t)b * N_SEQ * QKV_LD + 2048 + h * 64;
#pragma unroll
  for (int i = 0; i < 2; ++i) {
    const int cid = i * 256 + threadIdx.x;       // 0..511
    const int r = cid >> 3, c = (cid & 7) * 8;
    *(short8*)&t[r][c] = *(const short8*)(src + (size_t)(nt0 + r) * QKV_LD + c);
  }
  __syncthreads();
#pragma unroll
  for (int i = 0; i < 2; ++i) {
    const int cid = i * 256 + threadIdx.x;
    const int d = cid >> 3, c = (cid & 7) * 8;
    short8 v;
#pragma unroll
    for (int j = 0; j < 8; ++j) v[j] = t[c + j][d];
    *(short8*)(vt + ((size_t)bh * 64 + d) * N_SEQ + nt0 + c) = v;
  }
}

// ---------------- TN GEMM: C[M][N] = A[M][K] * Bt[N][K]^T  (m97 structure) ----------------
template <typename OutT>
__global__ __launch_bounds__(256) void gemm_tn(const u16* __restrict__ A,
                                               const u16* __restrict__ Bt,
                                               OutT* __restrict__ C,
                                               int M, int N, int K) {
  __shared__ u16 Al[128 * 64];
  __shared__ u16 Bl[128 * 64];
  const int tid = threadIdx.x;
  const int w = tid >> 6, lane = tid & 63;
  const int l15 = lane & 15, lg = lane >> 4;
  const int wr = w >> 1, wc = w & 1;
  const int m0 = blockIdx.y * 128, n0 = blockIdx.x * 128;

  f32x4 acc[4][4] = {};

  for (int k0 = 0; k0 < K; k0 += 64) {
#pragma unroll
    for (int i = 0; i < 4; ++i) {
      const int chunk = (w << 2) + i;
      const int e = (chunk << 9) + lane * 8;
      const int row = e >> 6, col = e & 63;
      const u16* ga = A + (size_t)(m0 + row) * K + k0 + col;
      __builtin_amdgcn_global_load_lds((gptr_t)ga, (sptr_t)(Al + (chunk << 9)), 16, 0, 0);
      const u16* gb = Bt + (size_t)(n0 + row) * K + k0 + col;
      __builtin_amdgcn_global_load_lds((gptr_t)gb, (sptr_t)(Bl + (chunk << 9)), 16, 0, 0);
    }
    __syncthreads();
#pragma unroll
    for (int kk = 0; kk < 2; ++kk) {
      short8 af[4], bf[4];
#pragma unroll
      for (int m = 0; m < 4; ++m)
        af[m] = *(const short8*)(Al + ((wr * 64 + m * 16 + l15) << 6) + kk * 32 + lg * 8);
#pragma unroll
      for (int n = 0; n < 4; ++n)
        bf[n] = *(const short8*)(Bl + ((wc * 64 + n * 16 + l15) << 6) + kk * 32 + lg * 8);
#pragma unroll
      for (int m = 0; m < 4; ++m)
#pragma unroll
        for (int n = 0; n < 4; ++n)
          acc[m][n] = __builtin_amdgcn_mfma_f32_16x16x32_bf16(af[m], bf[n], acc[m][n], 0, 0, 0);
    }
    __syncthreads();
  }

#pragma unroll
  for (int m = 0; m < 4; ++m)
#pragma unroll
    for (int n = 0; n < 4; ++n)
#pragma unroll
      for (int r = 0; r < 4; ++r) {
        const int row = m0 + wr * 64 + m * 16 + lg * 4 + r;
        const int col = n0 + wc * 64 + n * 16 + l15;
        const float v = acc[m][n][r];
        if constexpr (sizeof(OutT) == 2) C[(size_t)row * N + col] = (OutT)f2b(v);
        else                             C[(size_t)row * N + col] = (OutT)v;
      }
}

// ---------------- causal flash attention (swapped-operand, KVBLK=128) ----------------
// grid (32 bh, 32 qt-desc), 256 thr. Wave w owns q rows w*16..+16 (row = l15, replicated over lg).
__global__ __launch_bounds__(256) void attn_kernel(const u16* __restrict__ qkv,
                                                   const u16* __restrict__ vt,
                                                   u16* __restrict__ attnb) {
  const int bh = blockIdx.x;
  const int qt = 31 - (int)blockIdx.y;          // long blocks dispatch first
  const int b = bh >> 4, h = bh & 15;
  const int tid = threadIdx.x;
  const int lane = tid & 63, w = tid >> 6;
  const int l15 = lane & 15, lg = lane >> 4;
  const int q0 = qt * 64;
  const int qrow = q0 + w * 16 + l15;           // this thread's q row

  __shared__ u16 Kl[128 * 64];                  // K tile, 16B-chunk-swizzled
  __shared__ u16 Vl[64 * 128];                  // V^T tile, 16B-chunk-swizzled
  __shared__ u16 Pl[4][16][136];                // per-wave P relayout (pad 136: conflict-free)

  const u16* base  = qkv + (size_t)b * N_SEQ * QKV_LD;
  const u16* kbase = base + 1024 + h * 64;
  const u16* vbase = vt + (size_t)bh * 64 * N_SEQ;

  short8 aq[2];
  {
    const u16* qp = base + (size_t)qrow * QKV_LD + h * 64 + lg * 8;
    aq[0] = *(const short8*)qp;
    aq[1] = *(const short8*)(qp + 32);
  }

  f32x4 o[4] = {};
  float m_run = -3.0e38f, l_run = 0.f;
  const float kscale = 0.125f * 1.4426950408889634f;   // scale * log2(e)
  const int nt = (qt >> 1) + 1;
  const int wbase = tid & ~63;                  // wave-uniform

  for (int jt = 0; jt < nt; ++jt) {
    const int kv0 = jt * 128;
    __syncthreads();                            // prior tile reads done
#pragma unroll
    for (int i = 0; i < 4; ++i) {
      const int cid = i * 256 + tid;
      // K: 128 rows x 8 chunks of 16B, chunk swizzle c ^= row&7 applied at SOURCE
      const int krow = cid >> 3, kc = (cid & 7) ^ (krow & 7);
      const u16* ks = kbase + (size_t)(kv0 + krow) * QKV_LD + kc * 8;
      __builtin_amdgcn_global_load_lds((gptr_t)ks, (sptr_t)(Kl + (i * 256 + wbase) * 8), 16, 0, 0);
      // V^T: 64 rows x 16 chunks, swizzle low 3 bits of chunk
      const int vrow = cid >> 4, vc0 = cid & 15;
      const int vc = (vc0 & 8) | ((vc0 & 7) ^ (vrow & 7));
      const u16* vs = vbase + (size_t)vrow * N_SEQ + kv0 + vc * 8;
      __builtin_amdgcn_global_load_lds((gptr_t)vs, (sptr_t)(Vl + (i * 256 + wbase) * 8), 16, 0, 0);
    }
    __syncthreads();                            // vmcnt(0) drained by barrier

    // S^T = K·Q^T: p[mf][r] = S[q=l15][kv0 + mf*16 + lg*4 + r]  (unscaled)
    f32x4 p[8];
#pragma unroll
    for (int mf = 0; mf < 8; ++mf) {
      f32x4 acc = {};
#pragma unroll
      for (int ks = 0; ks < 2; ++ks) {
        const int row = mf * 16 + l15;
        const int ch = (ks * 4 + lg) ^ (row & 7);
        short8 ak = *(const short8*)(Kl + row * 64 + ch * 8);
        acc = __builtin_amdgcn_mfma_f32_16x16x32_bf16(ak, aq[ks], acc, 0, 0, 0);
      }
      p[mf] = acc;
    }

    if (jt == nt - 1) {                         // causal mask only on last tile
#pragma unroll
      for (int mf = 0; mf < 8; ++mf)
#pragma unroll
        for (int r = 0; r < 4; ++r)
          if (kv0 + mf * 16 + lg * 4 + r > qrow) p[mf][r] = -3.0e38f;
    }

    // lane-local softmax for row q=l15 (replicated over lg; reduce over lg groups)
    float mt = p[0][0];
#pragma unroll
    for (int mf = 0; mf < 8; ++mf)
#pragma unroll
      for (int r = 0; r < 4; ++r) mt = fmaxf(mt, p[mf][r]);
    mt = fmaxf(mt, __shfl_xor(mt, 16, 64));
    mt = fmaxf(mt, __shfl_xor(mt, 32, 64));
    const float mn = fmaxf(m_run, mt);
    const float sf = exp2f((m_run - mn) * kscale);
    m_run = mn;
    float psum = 0.f;
#pragma unroll
    for (int mf = 0; mf < 8; ++mf)
#pragma unroll
      for (int r = 0; r < 4; ++r) {
        const float e = exp2f((p[mf][r] - mn) * kscale);
        p[mf][r] = e;
        psum += e;
      }
    psum += __shfl_xor(psum, 16, 64);
    psum += __shfl_xor(psum, 32, 64);
    l_run = l_run * sf + psum;
#pragma unroll
    for (int mf = 0; mf < 4; ++mf) o[mf] *= sf;

    // P -> bf16 packed -> per-wave LDS (b64 writes), reread as PV B-operand
#pragma unroll
    for (int mf = 0; mf < 8; ++mf) {
      u32 d0, d1;
      asm("v_cvt_pk_bf16_f32 %0, %1, %2" : "=v"(d0) : "v"(p[mf][0]), "v"(p[mf][1]));
      asm("v_cvt_pk_bf16_f32 %0, %1, %2" : "=v"(d1) : "v"(p[mf][2]), "v"(p[mf][3]));
      u32x2 dd = {d0, d1};
      *(u32x2*)&Pl[w][l15][mf * 16 + lg * 4] = dd;
    }
    asm volatile("s_waitcnt lgkmcnt(0)" ::: "memory");

    short8 ap[4];
#pragma unroll
    for (int ks = 0; ks < 4; ++ks)
      ap[ks] = *(const short8*)&Pl[w][l15][ks * 32 + lg * 8];

    // O^T += V^T · P^T : o[mf] holds O[q=l15][d = mf*16 + lg*4 + r]
#pragma unroll
    for (int mf = 0; mf < 4; ++mf)
#pragma unroll
      for (int ks = 0; ks < 4; ++ks) {
        const int row = mf * 16 + l15;
        const int ch = ks * 4 + lg;
        const int csw = (ch & 8) | ((ch & 7) ^ (row & 7));
        short8 av = *(const short8*)(Vl + row * 128 + csw * 8);
        o[mf] = __builtin_amdgcn_mfma_f32_16x16x32_bf16(av, ap[ks], o[mf], 0, 0, 0);
      }
  }

  const float inv = 1.f / l_run;
#pragma unroll
  for (int mf = 0; mf < 4; ++mf) {
    s16x4 sv;
#pragma unroll
    for (int r = 0; r < 4; ++r) sv[r] = (short)f2b(o[mf][r] * inv);
    u16* op = attnb + ((size_t)b * N_SEQ + qrow) * INNER + h * 64 + mf * 16 + lg * 4;
    *(s16x4*)op = sv;
  }
}

extern "C" void kernel_launch(void* const* d_in, const int* in_sizes, int n_in,
                              void* d_out, int out_size, void* d_ws, size_t ws_size,
                              hipStream_t stream) {
  const float* x  = (const float*)d_in[0];
  const float* Wq = (const float*)d_in[1];
  const float* Wk = (const float*)d_in[2];
  const float* Wv = (const float*)d_in[3];
  const float* Wo = (const float*)d_in[4];
  float* out = (float*)d_out;

  // workspace layout (bf16 elements): 56 MB total
  u16* xb    = (u16*)d_ws;                               // [4096][1024]
  u16* wqkvt = xb    + (size_t)NTOK * DIM;               // [3072][1024]
  u16* wot   = wqkvt + (size_t)3 * INNER * DIM;          // [1024][1024]
  u16* qkv   = wot   + (size_t)DIM * INNER;              // [4096][3072]
  u16* attnb = qkv   + (size_t)NTOK * QKV_LD;            // [4096][1024]
  u16* vtb   = attnb + (size_t)NTOK * INNER;             // [32][64][2048]

  cast_x_kernel<<<dim3(NTOK * DIM / (256 * 8)), 256, 0, stream>>>(x, xb);
  transpose_cast_kernel<<<dim3(16, 16), 256, 0, stream>>>(Wq, wqkvt);
  transpose_cast_kernel<<<dim3(16, 16), 256, 0, stream>>>(Wk, wqkvt + (size_t)1024 * 1024);
  transpose_cast_kernel<<<dim3(16, 16), 256, 0, stream>>>(Wv, wqkvt + (size_t)2048 * 1024);
  transpose_cast_kernel<<<dim3(16, 16), 256, 0, stream>>>(Wo, wot);

  gemm_tn<u16><<<dim3(3072 / 128, 4096 / 128), 256, 0, stream>>>(xb, wqkvt, qkv, NTOK, 3072, DIM);
  transpose_v_kernel<<<dim3(32, 32), 256, 0, stream>>>(qkv, vtb);
  attn_kernel<<<dim3(32, 32), 256, 0, stream>>>(qkv, vtb, attnb);
  gemm_tn<float><<<dim3(1024 / 128, 4096 / 128), 256, 0, stream>>>(attnb, wot, out, NTOK, INNER, INNER);
}